// Round 1
// baseline (270.913 us; speedup 1.0000x reference)
//
#include <hip/hip_runtime.h>

typedef _Float16 half_t;
typedef __attribute__((ext_vector_type(8))) _Float16 half8;
typedef __attribute__((ext_vector_type(4))) _Float16 half4;
typedef __attribute__((ext_vector_type(4))) float float4v;

#define LN_EPS 1e-5f
#define QK_SCALE 0.17677669529663687f   // 32^-0.5

static __device__ __forceinline__ float4v mfma_16x16x32(half8 a, half8 b, float4v c) {
    return __builtin_amdgcn_mfma_f32_16x16x32_f16(a, b, c, 0, 0, 0);
}

// XOR-swizzled byte offset into a row-major LDS tile with 512B rows (256 fp16)
static __device__ __forceinline__ int swz512(int row, int colByte) {
    return row * 512 + ((((colByte >> 4) ^ (row & 7)) << 4) | (colByte & 15));
}
// 128B rows (64 fp16)
static __device__ __forceinline__ int swz128(int row, int colByte) {
    return row * 128 + ((((colByte >> 4) ^ (row & 7)) << 4) | (colByte & 15));
}

static __device__ void ln_relu16(float* h, const float* __restrict__ g, const float* __restrict__ b) {
    float m = 0.f;
    for (int j = 0; j < 16; ++j) m += h[j];
    m *= (1.0f / 16.0f);
    float v = 0.f;
    for (int j = 0; j < 16; ++j) { float d = h[j] - m; v += d * d; }
    v *= (1.0f / 16.0f);
    float rs = rsqrtf(v + LN_EPS);
    for (int j = 0; j < 16; ++j) {
        float t = (h[j] - m) * rs * g[j] + b[j];
        h[j] = t > 0.f ? t : 0.f;
    }
}

// ---------------------------------------------------------------------------
// prep: weight transpose+fp16 convert, pos-bias MLP, rel_bias expansion
// grid: 65 blocks x 256 threads. blocks 0..47: qkv_w tiles; 48..63: proj_w
// tiles; 64: MLP + rel_bias.
// ---------------------------------------------------------------------------
__global__ void prep_kernel(
    const float* __restrict__ qkv_w,   // [256,768]
    const float* __restrict__ proj_w,  // [256,256]
    const float* __restrict__ biases,  // [225,2]
    const float* __restrict__ pos_w, const float* __restrict__ pos_b,
    const float* __restrict__ ln1_g, const float* __restrict__ ln1_b,
    const float* __restrict__ fc1_w, const float* __restrict__ fc1_b,
    const float* __restrict__ ln2_g, const float* __restrict__ ln2_b,
    const float* __restrict__ fc2_w, const float* __restrict__ fc2_b,
    const float* __restrict__ ln3_g, const float* __restrict__ ln3_b,
    const float* __restrict__ fc3_w, const float* __restrict__ fc3_b,
    const int* __restrict__ rel_idx,   // [64,64]
    half_t* __restrict__ wqkvT,        // [768,256]  wqkvT[c][k] = qkv_w[k][c]
    half_t* __restrict__ wprojT,       // [256,256]  wprojT[c][k] = proj_w[k][c]
    float* __restrict__ rel_bias)      // [8,64,64]
{
    __shared__ float tile[64][65];
    __shared__ float pos_s[225][8];
    const int t = blockIdx.x;
    const int tid = threadIdx.x;

    if (t < 64) {
        const float* src; half_t* dst; int ncols, rg, cg;
        if (t < 48) { src = qkv_w;  dst = wqkvT;  ncols = 768; rg = t / 12;      cg = t % 12; }
        else        { src = proj_w; dst = wprojT; ncols = 256; rg = (t-48) >> 2; cg = (t-48) & 3; }
        const int r0 = tid >> 6, c = tid & 63;
        for (int i = 0; i < 16; ++i) {
            int r = i * 4 + r0;
            tile[r][c] = src[(rg * 64 + r) * ncols + cg * 64 + c];
        }
        __syncthreads();
        for (int i = 0; i < 16; ++i) {
            int r = i * 4 + r0;
            dst[(cg * 64 + r) * 256 + rg * 64 + c] = (half_t)tile[c][r];
        }
    } else {
        if (tid < 225) {
            float h[16], h2[16];
            float b0 = biases[tid * 2], b1 = biases[tid * 2 + 1];
            for (int j = 0; j < 16; ++j) h[j] = b0 * pos_w[j] + b1 * pos_w[16 + j] + pos_b[j];
            ln_relu16(h, ln1_g, ln1_b);
            for (int j = 0; j < 16; ++j) {
                float s = fc1_b[j];
                for (int k = 0; k < 16; ++k) s += h[k] * fc1_w[k * 16 + j];
                h2[j] = s;
            }
            ln_relu16(h2, ln2_g, ln2_b);
            for (int j = 0; j < 16; ++j) {
                float s = fc2_b[j];
                for (int k = 0; k < 16; ++k) s += h2[k] * fc2_w[k * 16 + j];
                h[j] = s;
            }
            ln_relu16(h, ln3_g, ln3_b);
            for (int j = 0; j < 8; ++j) {
                float s = fc3_b[j];
                for (int k = 0; k < 16; ++k) s += h[k] * fc3_w[k * 8 + j];
                pos_s[tid][j] = s;
            }
        }
        __syncthreads();
        for (int e = tid; e < 8 * 64 * 64; e += 256) {
            int hh = e >> 12, nm = e & 4095;
            rel_bias[e] = pos_s[rel_idx[nm]][hh];
        }
    }
}

// ---------------------------------------------------------------------------
// fused: per-window  x -> qkv -> attention(+bias, softmax) -> proj -> out
// grid: B windows x 512 threads (8 waves; wave w owns head w in attention).
// LDS 128KB: xs[64][256] | qs[64][256] | ks[64][256](->attn_out) | vT[256][64]
// xs+qs reused as the 8x8KB per-wave P arenas after S is computed.
// ---------------------------------------------------------------------------
__global__ __launch_bounds__(512, 2) void fused_kernel(
    const float* __restrict__ x,
    const half_t* __restrict__ wqkvT,
    const float* __restrict__ qkv_b,
    const half_t* __restrict__ wprojT,
    const float* __restrict__ proj_b,
    const float* __restrict__ rel_bias,
    float* __restrict__ out)
{
    __shared__ __align__(16) char smem[131072];
    char* xs = smem;             // [64][256] f16, swizzled 512B rows
    char* qs = smem + 32768;
    char* ks = smem + 65536;     // later attn_out
    char* vt = smem + 98304;     // [256][64] f16, swizzled 128B rows

    const int b   = blockIdx.x;
    const int tid = threadIdx.x;
    const int w   = tid >> 6;    // wave 0..7
    const int lane = tid & 63;
    const int m = lane & 15;     // tile col
    const int g = lane >> 4;     // k-group 0..3

    // ---- phase 0: x -> xs (fp16, swizzled) ----
    const float* xg = x + (size_t)b * (64 * 256);
    #pragma unroll
    for (int i = 0; i < 8; ++i) {
        int u = tid + i * 512;               // float4 unit, 0..4095
        int row = u >> 6, c4 = u & 63;
        float4v xv = *(const float4v*)(xg + u * 4);
        half4 hv;
        hv[0] = (half_t)xv[0]; hv[1] = (half_t)xv[1];
        hv[2] = (half_t)xv[2]; hv[3] = (half_t)xv[3];
        *(half4*)(xs + swz512(row, c4 * 8)) = hv;
    }
    __syncthreads();   // B1

    // ---- phase 1: QKV GEMM. 48 col-tiles of 16; wave w -> tiles w*6..w*6+5 ----
    for (int ct6 = 0; ct6 < 6; ++ct6) {
        const int ct = w * 6 + ct6;
        half8 bfr[8];
        const half_t* wb = wqkvT + (ct * 16 + m) * 256 + g * 8;
        #pragma unroll
        for (int kk = 0; kk < 8; ++kk) bfr[kk] = *(const half8*)(wb + kk * 32);
        const float bias = qkv_b[ct * 16 + m];
        #pragma unroll
        for (int ti = 0; ti < 4; ++ti) {
            float4v acc = {0.f, 0.f, 0.f, 0.f};
            #pragma unroll
            for (int kk = 0; kk < 8; ++kk) {
                half8 af = *(const half8*)(xs + swz512(ti * 16 + m, kk * 64 + g * 16));
                acc = mfma_16x16x32(af, bfr[kk], acc);
            }
            if (ct < 16) {              // q: cols 0..255
                int colB = (ct * 16 + m) * 2;
                #pragma unroll
                for (int r = 0; r < 4; ++r)
                    *(half_t*)(qs + swz512(ti * 16 + g * 4 + r, colB)) = (half_t)(acc[r] + bias);
            } else if (ct < 32) {       // k: cols 256..511
                int colB = ((ct - 16) * 16 + m) * 2;
                #pragma unroll
                for (int r = 0; r < 4; ++r)
                    *(half_t*)(ks + swz512(ti * 16 + g * 4 + r, colB)) = (half_t)(acc[r] + bias);
            } else {                    // v: cols 512..767 -> vT[d][n]
                int d = (ct - 32) * 16 + m;
                half4 pv;
                #pragma unroll
                for (int r = 0; r < 4; ++r) pv[r] = (half_t)(acc[r] + bias);
                *(half4*)(vt + swz128(d, (ti * 16 + g * 4) * 2)) = pv;
            }
        }
    }
    __syncthreads();   // B2: q/k/vT ready

    // ---- phase 2: S = q k^T (head h = w) ----
    const int h = w;
    half8 bk[4];
    #pragma unroll
    for (int tj = 0; tj < 4; ++tj)
        bk[tj] = *(const half8*)(ks + swz512(tj * 16 + m, h * 64 + g * 16));
    float4v sacc[4][4];
    #pragma unroll
    for (int ti = 0; ti < 4; ++ti) {
        half8 aq = *(const half8*)(qs + swz512(ti * 16 + m, h * 64 + g * 16));
        #pragma unroll
        for (int tj = 0; tj < 4; ++tj) {
            float4v z = {0.f, 0.f, 0.f, 0.f};
            sacc[ti][tj] = mfma_16x16x32(aq, bk[tj], z);
        }
    }
    __syncthreads();   // B3: all q/k reads done -> xs/qs (P arenas) reusable

    // ---- phase 3: bias + softmax, P -> per-wave LDS arena ----
    const float* rb = rel_bias + h * 4096;
    char* pw = smem + w * 8192;          // wave-private 64x64 f16
    float rinv[4][4];
    #pragma unroll
    for (int ti = 0; ti < 4; ++ti) {
        #pragma unroll
        for (int r = 0; r < 4; ++r) {
            int row = ti * 16 + g * 4 + r;
            float v0 = sacc[ti][0][r] * QK_SCALE + rb[row * 64 + m];
            float v1 = sacc[ti][1][r] * QK_SCALE + rb[row * 64 + 16 + m];
            float v2 = sacc[ti][2][r] * QK_SCALE + rb[row * 64 + 32 + m];
            float v3 = sacc[ti][3][r] * QK_SCALE + rb[row * 64 + 48 + m];
            float mx = fmaxf(fmaxf(v0, v1), fmaxf(v2, v3));
            mx = fmaxf(mx, __shfl_xor(mx, 1));
            mx = fmaxf(mx, __shfl_xor(mx, 2));
            mx = fmaxf(mx, __shfl_xor(mx, 4));
            mx = fmaxf(mx, __shfl_xor(mx, 8));
            float e0 = __expf(v0 - mx), e1 = __expf(v1 - mx);
            float e2 = __expf(v2 - mx), e3 = __expf(v3 - mx);
            float s = e0 + e1 + e2 + e3;
            s += __shfl_xor(s, 1); s += __shfl_xor(s, 2);
            s += __shfl_xor(s, 4); s += __shfl_xor(s, 8);
            rinv[ti][r] = 1.0f / s;
            *(half_t*)(pw + swz128(row, 2 * m))      = (half_t)e0;
            *(half_t*)(pw + swz128(row, 2 * m + 32)) = (half_t)e1;
            *(half_t*)(pw + swz128(row, 2 * m + 64)) = (half_t)e2;
            *(half_t*)(pw + swz128(row, 2 * m + 96)) = (half_t)e3;
        }
    }

    // ---- phase 4: PV, write attn_out (ks arena) ----
    half8 bv[2][2];
    #pragma unroll
    for (int tjd = 0; tjd < 2; ++tjd)
        #pragma unroll
        for (int kk = 0; kk < 2; ++kk)
            bv[tjd][kk] = *(const half8*)(vt + swz128(h * 32 + tjd * 16 + m, kk * 64 + g * 16));
    #pragma unroll
    for (int ti = 0; ti < 4; ++ti) {
        half8 pa0 = *(const half8*)(pw + swz128(ti * 16 + m, g * 16));
        half8 pa1 = *(const half8*)(pw + swz128(ti * 16 + m, 64 + g * 16));
        #pragma unroll
        for (int tjd = 0; tjd < 2; ++tjd) {
            float4v o = {0.f, 0.f, 0.f, 0.f};
            o = mfma_16x16x32(pa0, bv[tjd][0], o);
            o = mfma_16x16x32(pa1, bv[tjd][1], o);
            #pragma unroll
            for (int r = 0; r < 4; ++r) {
                float val = o[r] * rinv[ti][r];
                *(half_t*)(ks + swz512(ti * 16 + g * 4 + r, (h * 32 + tjd * 16 + m) * 2)) = (half_t)val;
            }
        }
    }
    __syncthreads();   // B4: attn_out ready

    // ---- phase 5: proj GEMM + bias -> out (fp32) ----
    float* og = out + (size_t)b * (64 * 256);
    #pragma unroll
    for (int cti = 0; cti < 2; ++cti) {
        const int ct = w * 2 + cti;
        half8 bf[8];
        const half_t* wb = wprojT + (ct * 16 + m) * 256 + g * 8;
        #pragma unroll
        for (int kk = 0; kk < 8; ++kk) bf[kk] = *(const half8*)(wb + kk * 32);
        const float pb = proj_b[ct * 16 + m];
        #pragma unroll
        for (int ti = 0; ti < 4; ++ti) {
            float4v acc = {0.f, 0.f, 0.f, 0.f};
            #pragma unroll
            for (int kk = 0; kk < 8; ++kk) {
                half8 af = *(const half8*)(ks + swz512(ti * 16 + m, kk * 64 + g * 16));
                acc = mfma_16x16x32(af, bf[kk], acc);
            }
            #pragma unroll
            for (int r = 0; r < 4; ++r)
                og[(ti * 16 + g * 4 + r) * 256 + ct * 16 + m] = acc[r] + pb;
        }
    }
}

extern "C" void kernel_launch(void* const* d_in, const int* in_sizes, int n_in,
                              void* d_out, int out_size, void* d_ws, size_t ws_size,
                              hipStream_t stream) {
    const float* x          = (const float*)d_in[0];
    const float* qkv_w      = (const float*)d_in[1];
    const float* qkv_b      = (const float*)d_in[2];
    const float* proj_w     = (const float*)d_in[3];
    const float* proj_b     = (const float*)d_in[4];
    const float* pos_proj_w = (const float*)d_in[5];
    const float* pos_proj_b = (const float*)d_in[6];
    const float* ln1_g = (const float*)d_in[7];
    const float* ln1_b = (const float*)d_in[8];
    const float* fc1_w = (const float*)d_in[9];
    const float* fc1_b = (const float*)d_in[10];
    const float* ln2_g = (const float*)d_in[11];
    const float* ln2_b = (const float*)d_in[12];
    const float* fc2_w = (const float*)d_in[13];
    const float* fc2_b = (const float*)d_in[14];
    const float* ln3_g = (const float*)d_in[15];
    const float* ln3_b = (const float*)d_in[16];
    const float* fc3_w = (const float*)d_in[17];
    const float* fc3_b = (const float*)d_in[18];
    const float* biases = (const float*)d_in[19];
    const int*  rel_idx = (const int*)d_in[20];

    half_t* wqkvT    = (half_t*)d_ws;
    half_t* wprojT   = (half_t*)((char*)d_ws + 393216);
    float*  rel_bias = (float*)((char*)d_ws + 524288);

    const int B = in_sizes[0] / (64 * 256);

    prep_kernel<<<65, 256, 0, stream>>>(qkv_w, proj_w, biases, pos_proj_w, pos_proj_b,
                                        ln1_g, ln1_b, fc1_w, fc1_b,
                                        ln2_g, ln2_b, fc2_w, fc2_b,
                                        ln3_g, ln3_b, fc3_w, fc3_b,
                                        rel_idx, wqkvT, wprojT, rel_bias);
    fused_kernel<<<B, 512, 0, stream>>>(x, wqkvT, qkv_b, wprojT, proj_b, rel_bias,
                                        (float*)d_out);
}